// Round 12
// baseline (195.945 us; speedup 1.0000x reference)
//
#include <hip/hip_runtime.h>
#include <hip/hip_fp16.h>

typedef _Float16 f16x8 __attribute__((ext_vector_type(8)));
typedef float f32x4 __attribute__((ext_vector_type(4)));

__device__ __forceinline__ f32x4 ntld4(const float* p) {
    return __builtin_nontemporal_load((const f32x4*)p);
}
__device__ __forceinline__ float ntld1(const float* p) {
    return __builtin_nontemporal_load(p);
}
__device__ __forceinline__ f32x4 ld4(const float* p) {
    return *(const f32x4*)p;
}
__device__ __forceinline__ void ntst4(float* p, f32x4 v) {
    __builtin_nontemporal_store(v, (f32x4*)p);
}

// ---------------------------------------------------------------------------
// prep: per head h, W[h] = mv[h] @ mk[h]^T (f16 [n][n']) and mkT[h] (f16
// [m][n]) into workspace. norm-divide commutes (depends only on d), so both
// outputs become GEMMs against q with contraction over n.
// ---------------------------------------------------------------------------
__global__ __launch_bounds__(256) void prep(
    const float* __restrict__ mk, const float* __restrict__ mv,
    _Float16* __restrict__ mkTb, _Float16* __restrict__ Wb)
{
    __shared__ _Float16 mks[64][72];
    __shared__ _Float16 mvs[64][72];
    const int t = threadIdx.x;
    const int h = blockIdx.x;
    const float* mkb = mk + h * 4096;
    const float* mvb = mv + h * 4096;
    {
        const int nn = t >> 2, m0 = (t & 3) * 16;
        f32x4 a0 = ld4(mkb + nn * 64 + m0),     a1 = ld4(mkb + nn * 64 + m0 + 4);
        f32x4 a2 = ld4(mkb + nn * 64 + m0 + 8), a3 = ld4(mkb + nn * 64 + m0 + 12);
        f32x4 b0 = ld4(mvb + nn * 64 + m0),     b1 = ld4(mvb + nn * 64 + m0 + 4);
        f32x4 b2 = ld4(mvb + nn * 64 + m0 + 8), b3 = ld4(mvb + nn * 64 + m0 + 12);
        f16x8 k0, k1, v0, v1;
#pragma unroll
        for (int i = 0; i < 4; ++i) {
            k0[i] = (_Float16)a0[i]; k0[i + 4] = (_Float16)a1[i];
            k1[i] = (_Float16)a2[i]; k1[i + 4] = (_Float16)a3[i];
            v0[i] = (_Float16)b0[i]; v0[i + 4] = (_Float16)b1[i];
            v1[i] = (_Float16)b2[i]; v1[i + 4] = (_Float16)b3[i];
        }
        *(f16x8*)&mks[nn][m0]     = k0;
        *(f16x8*)&mks[nn][m0 + 8] = k1;
        *(f16x8*)&mvs[nn][m0]     = v0;
        *(f16x8*)&mvs[nn][m0 + 8] = v1;
    }
    __syncthreads();
    const int w = t >> 6, l = t & 63, lr = l & 15, lk = l >> 4;
    f32x4 acc[4] = {};
#pragma unroll
    for (int kn = 0; kn < 2; ++kn) {
        f16x8 bfr = *(const f16x8*)&mks[16 * w + lr][kn * 32 + lk * 8];
#pragma unroll
        for (int di = 0; di < 4; ++di) {
            f16x8 afr = *(const f16x8*)&mvs[16 * di + lr][kn * 32 + lk * 8];
            acc[di] = __builtin_amdgcn_mfma_f32_16x16x32_f16(afr, bfr, acc[di], 0, 0, 0);
        }
    }
#pragma unroll
    for (int di = 0; di < 4; ++di)
#pragma unroll
        for (int r = 0; r < 4; ++r)
            Wb[h * 4096 + (16 * di + 4 * lk + r) * 64 + 16 * w + lr] = (_Float16)acc[di][r];
    {
        const int m = t & 63, n0 = (t >> 6) * 16;
        f16x8 x0, x1;
#pragma unroll
        for (int i = 0; i < 8; ++i) { x0[i] = mks[n0 + i][m]; x1[i] = mks[n0 + 8 + i][m]; }
        *(f16x8*)&mkTb[h * 4096 + m * 64 + n0]     = x0;
        *(f16x8*)&mkTb[h * 4096 + m * 64 + n0 + 8] = x1;
    }
}

// ---------------------------------------------------------------------------
// Mega kernel.
//  Blocks [0, nbR): reduction over key/value tiles (grid-stride, prefetched).
//  Blocks [nbR, nbR+8192): fused path. One block per (b,h) tile; wave w owns
//  d-quarter di=w for ALL 4 m-stripes:
//    - A-fragments (16 scalar nt loads/thread) are DISJOINT across waves ->
//      zero q redundancy at full 8192-block parallelism (fix of R11's
//      occupancy loss and R10's 4x load redundancy simultaneously).
//    - B-fragments (mkT/W rows) identical across waves -> L1 broadcast.
//    - 16 MFMAs, 8 nt f32x4 stores per thread. Zero barriers, zero LDS.
// ---------------------------------------------------------------------------
__global__ __launch_bounds__(256) void mega(
    const float* __restrict__ q,   const float* __restrict__ key,
    const float* __restrict__ val, const _Float16* __restrict__ mkTb,
    const float* __restrict__ mnorm, const _Float16* __restrict__ Wb,
    float* __restrict__ out_mo, float* __restrict__ out_sc,
    float* __restrict__ skp, float* __restrict__ svp, float* __restrict__ pbp,
    const int nbR)
{
    __shared__ struct { float ktile[64][68]; float red[256]; float ks[64]; } smr;

    const int t   = threadIdx.x;
    const int bid = blockIdx.x;

    if (bid < nbR) {
        // ================= reduction path =================
        const int r0 = t >> 4;
        const int c0 = (t & 15) << 2;
        f32x4 ska[4] = {}; f32x4 sva[4] = {};
        float pba[4] = {0.f, 0.f, 0.f, 0.f};
        f32x4 ka[4], va[4];
        int i = bid;
#pragma unroll
        for (int qq = 0; qq < 4; ++qq) {
            const int row = r0 + 16 * qq;
            ka[qq] = ntld4(key + (size_t)i * 4096 + row * 64 + c0);
            va[qq] = ntld4(val + (size_t)i * 4096 + row * 64 + c0);
        }
        while (true) {
            const int inx = i + nbR;
            const bool more = (inx < 8192);
            f32x4 kn4[4], vn4[4];
            if (more) {
#pragma unroll
                for (int qq = 0; qq < 4; ++qq) {
                    const int row = r0 + 16 * qq;
                    kn4[qq] = ntld4(key + (size_t)inx * 4096 + row * 64 + c0);
                    vn4[qq] = ntld4(val + (size_t)inx * 4096 + row * 64 + c0);
                }
            }
#pragma unroll
            for (int qq = 0; qq < 4; ++qq) {
                const int row = r0 + 16 * qq;
                ska[qq] += ka[qq];
                sva[qq] += va[qq];
                *(f32x4*)&smr.ktile[row][c0] = ka[qq];
            }
            __syncthreads();
            {   // ks[d] = sum_n ktile[n][d]
                const int d  = t & 63;
                const int rr = (t >> 6) * 16;
                float p = 0.f;
#pragma unroll
                for (int r = 0; r < 16; ++r) p += smr.ktile[rr + r][d];
                smr.red[t] = p;
            }
            __syncthreads();
            if (t < 64)
                smr.ks[t] = smr.red[t] + smr.red[t + 64] + smr.red[t + 128] + smr.red[t + 192];
            __syncthreads();
#pragma unroll
            for (int qq = 0; qq < 4; ++qq) {
                float pq = va[qq][0] * smr.ks[c0]     + va[qq][1] * smr.ks[c0 + 1]
                         + va[qq][2] * smr.ks[c0 + 2] + va[qq][3] * smr.ks[c0 + 3];
                pq += __shfl_xor(pq, 1);
                pq += __shfl_xor(pq, 2);
                pq += __shfl_xor(pq, 4);
                pq += __shfl_xor(pq, 8);
                pba[qq] += pq;
            }
            if (!more) break;
#pragma unroll
            for (int qq = 0; qq < 4; ++qq) { ka[qq] = kn4[qq]; va[qq] = vn4[qq]; }
            i = inx;
        }
        const size_t pb4 = (size_t)bid * 4096;
#pragma unroll
        for (int qq = 0; qq < 4; ++qq) {
            ntst4(skp + pb4 + 4 * t + 1024 * qq, ska[qq]);
            ntst4(svp + pb4 + 4 * t + 1024 * qq, sva[qq]);
        }
        if ((t & 15) == 0) {
#pragma unroll
            for (int qq = 0; qq < 4; ++qq)
                pbp[bid * 64 + r0 + 16 * qq] = pba[qq];
        }
        return;
    }

    // ============ fused path: wave w owns d-quarter di=w, all m ============
    const int fid = bid - nbR;
    const int h   = fid >> 7;          // h-major
    const int b   = fid & 127;
    const int bh  = b * 64 + h;
    const float* qb = q + (size_t)bh * 4096;

    const int w  = t >> 6;             // d-quarter
    const int l  = t & 63;
    const int lr = l & 15;
    const int lk = l >> 4;

    // A-fragments for d-quarter w: afr[kn][e] = q[kn*32+lk*8+e][16w+lr]
    // (disjoint across waves -> zero redundancy; 16 loads/thread)
    f16x8 afr[2];
    {
        const float* qcol = qb + 16 * w + lr;
#pragma unroll
        for (int kn = 0; kn < 2; ++kn) {
            const float* p0 = qcol + (kn * 32 + lk * 8) * 64;
            f16x8 a;
#pragma unroll
            for (int e = 0; e < 8; ++e) a[e] = (_Float16)ntld1(p0 + e * 64);
            afr[kn] = a;
        }
    }

    // scale for this wave's d-rows: d = 16w + 4lk + r
    f32x4 scl;
    {
        f32x4 nv = ld4(mnorm + 16 * w + 4 * lk);
#pragma unroll
        for (int r = 0; r < 4; ++r) scl[r] = __builtin_amdgcn_rcpf(nv[r] + 1e-6f);
    }

    const size_t gbase = (size_t)bh * 4096;
    const int d0 = 16 * w + 4 * lk;

    // all 4 m-stripes; B-fragments identical across waves -> L1 broadcast
    f32x4 accS[4] = {}, accO[4] = {};
#pragma unroll
    for (int ms = 0; ms < 4; ++ms) {
        const _Float16* mrow = mkTb + h * 4096 + (16 * ms + lr) * 64 + lk * 8;
        const _Float16* wrow = Wb   + h * 4096 + (16 * ms + lr) * 64 + lk * 8;
        f16x8 bk0 = *(const f16x8*)(mrow);
        f16x8 bk1 = *(const f16x8*)(mrow + 32);
        f16x8 bw0 = *(const f16x8*)(wrow);
        f16x8 bw1 = *(const f16x8*)(wrow + 32);
        accS[ms] = __builtin_amdgcn_mfma_f32_16x16x32_f16(afr[0], bk0, accS[ms], 0, 0, 0);
        accS[ms] = __builtin_amdgcn_mfma_f32_16x16x32_f16(afr[1], bk1, accS[ms], 0, 0, 0);
        accO[ms] = __builtin_amdgcn_mfma_f32_16x16x32_f16(afr[0], bw0, accO[ms], 0, 0, 0);
        accO[ms] = __builtin_amdgcn_mfma_f32_16x16x32_f16(afr[1], bw1, accO[ms], 0, 0, 0);
    }

#pragma unroll
    for (int ms = 0; ms < 4; ++ms) {
        const int m = 16 * ms + lr;
        f32x4 sv, ov;
#pragma unroll
        for (int r = 0; r < 4; ++r) {
            sv[r] = accS[ms][r] * scl[r];
            ov[r] = accO[ms][r] * scl[r];
        }
        ntst4(out_sc + gbase + (size_t)m * 64 + d0, sv);
        ntst4(out_mo + gbase + (size_t)m * 64 + d0, ov);
    }
}

// Stage 2: NC n-chunks x 33 strips -> p2[NC][8256]
#define NCHUNK 8
__global__ __launch_bounds__(256) void reduce2(
    const float* __restrict__ skp, const float* __restrict__ svp,
    const float* __restrict__ pbp, float* __restrict__ p2,
    const int nbR, const int clen)
{
    const int bi = blockIdx.x;
    const int c  = bi / 33;
    const int e  = (bi % 33) * 256 + threadIdx.x;
    if (e >= 8256) return;
    int n0 = c * clen;
    int n1 = n0 + clen; if (n1 > nbR) n1 = nbR;
    float s = 0.f;
    if (e < 4096) {
        for (int n = n0; n < n1; ++n) s += skp[(size_t)n * 4096 + e];
    } else if (e < 8192) {
        const int e2 = e - 4096;
        for (int n = n0; n < n1; ++n) s += svp[(size_t)n * 4096 + e2];
    } else {
        const int e2 = e - 8192;
        for (int n = n0; n < n1; ++n) s += pbp[n * 64 + e2];
    }
    p2[c * 8256 + e] = s;
}

// Stage 3: finalize — sum the NC chunks, norms, compression factor, outputs.
__global__ __launch_bounds__(256) void finalize(
    const float* __restrict__ p2, const float* __restrict__ mnorm,
    const float* __restrict__ crate,
    float* __restrict__ out_nmk, float* __restrict__ out_nmn)
{
    __shared__ float tot[8256];
    __shared__ float fac_s[64];
    const int t = threadIdx.x;
    for (int e = t; e < 8256; e += 256) {
        float s = 0.f;
#pragma unroll
        for (int c = 0; c < NCHUNK; ++c) s += p2[c * 8256 + e];
        tot[e] = s;
    }
    __syncthreads();
    const float* sk_tot = tot;
    const float* sv_tot = tot + 4096;
    const float* pb_tot = tot + 8192;
    if (t < 64) {
        float ss = 0.f;
#pragma unroll 8
        for (int dd = 0; dd < 64; ++dd) {
            float mkm = sk_tot[t * 64 + dd] * (1.0f / 8192.0f);
            ss += mkm * mkm;
        }
        const float nmn = mnorm[t] + sqrtf(ss);
        float v = nmn;
        for (int off = 32; off; off >>= 1) v += __shfl_xor(v, off);
        const float mean = v * (1.0f / 64.0f);
        const float f = (mean > 0.9f) ? crate[t] : 1.0f;
        fac_s[t] = f;
        out_nmn[t] = nmn * f;
    }
    __syncthreads();
    for (int e = t; e < 4096; e += 256) {
        const int jh = e >> 6;
        const float mb = pb_tot[jh] * (1.0f / 524288.0f);   // mean binding
        const float mvv = sv_tot[e] * (1.0f / 8192.0f);     // mean value
        out_nmk[e] = mb * mvv * fac_s[jh];
    }
}

extern "C" void kernel_launch(void* const* d_in, const int* in_sizes, int n_in,
                              void* d_out, int out_size, void* d_ws, size_t ws_size,
                              hipStream_t stream) {
    const float* q  = (const float*)d_in[0];
    const float* k  = (const float*)d_in[1];
    const float* v  = (const float*)d_in[2];
    const float* mk = (const float*)d_in[3];
    const float* mn = (const float*)d_in[4];
    const float* mv = (const float*)d_in[5];
    const float* cr = (const float*)d_in[6];

    float* out     = (float*)d_out;
    float* out_mo  = out;                    // [128,64,64,64]
    float* out_sc  = out + 33554432;         // [128,64,64,64]
    float* out_nmk = out + 67108864;         // [64,64]
    float* out_nmn = out + 67112960;         // [64]

    float* ws   = (float*)d_ws;
    float* p2   = ws;                        // NCHUNK*8256 floats
    _Float16* mkTb = (_Float16*)(ws + NCHUNK * 8256);   // 262144 halves
    _Float16* Wb   = mkTb + 64 * 4096;                  // 262144 halves
    float* part = ws + NCHUNK * 8256 + 262144;
    const size_t wsf = ws_size / 4;
    const size_t used = NCHUNK * 8256 + 262144;
    const size_t avail = (wsf > used) ? (wsf - used) : 0;
    int nb = (int)(avail / 8256);
    if (nb > 256) nb = 256;
    if (nb < 1)   nb = 1;
    float* skp = part;
    float* svp = part + (size_t)nb * 4096;
    float* pbp = svp  + (size_t)nb * 4096;
    const int clen = (nb + NCHUNK - 1) / NCHUNK;

    hipLaunchKernelGGL(prep, dim3(64), dim3(256), 0, stream,
                       mk, mv, mkTb, Wb);
    hipLaunchKernelGGL(mega, dim3(nb + 8192), dim3(256), 0, stream,
                       q, k, v, mkTb, mn, Wb, out_mo, out_sc, skp, svp, pbp, nb);
    hipLaunchKernelGGL(reduce2, dim3(33 * NCHUNK), dim3(256), 0, stream,
                       skp, svp, pbp, p2, nb, clen);
    hipLaunchKernelGGL(finalize, dim3(1), dim3(256), 0, stream,
                       p2, mn, cr, out_nmk, out_nmn);
}

// Round 13
// 157.246 us; speedup vs baseline: 1.2461x; 1.2461x over previous
//
#include <hip/hip_runtime.h>
#include <hip/hip_fp16.h>

typedef _Float16 f16x8 __attribute__((ext_vector_type(8)));
typedef float f32x4 __attribute__((ext_vector_type(4)));

__device__ __forceinline__ f32x4 ntld4(const float* p) {
    return __builtin_nontemporal_load((const f32x4*)p);
}
__device__ __forceinline__ f32x4 ld4(const float* p) {
    return *(const f32x4*)p;
}
__device__ __forceinline__ void ntst4(float* p, f32x4 v) {
    __builtin_nontemporal_store(v, (f32x4*)p);
}

// ---------------------------------------------------------------------------
// prep: per head h, W[h] = mv[h] @ mk[h]^T (f16 [n][n']) and mkT[h] (f16
// [m][n]) into workspace. norm-divide commutes (depends only on d), so both
// outputs become GEMMs against q with contraction over n.
// ---------------------------------------------------------------------------
__global__ __launch_bounds__(256) void prep(
    const float* __restrict__ mk, const float* __restrict__ mv,
    _Float16* __restrict__ mkTb, _Float16* __restrict__ Wb)
{
    __shared__ _Float16 mks[64][72];
    __shared__ _Float16 mvs[64][72];
    const int t = threadIdx.x;
    const int h = blockIdx.x;
    const float* mkb = mk + h * 4096;
    const float* mvb = mv + h * 4096;
    {
        const int nn = t >> 2, m0 = (t & 3) * 16;
        f32x4 a0 = ld4(mkb + nn * 64 + m0),     a1 = ld4(mkb + nn * 64 + m0 + 4);
        f32x4 a2 = ld4(mkb + nn * 64 + m0 + 8), a3 = ld4(mkb + nn * 64 + m0 + 12);
        f32x4 b0 = ld4(mvb + nn * 64 + m0),     b1 = ld4(mvb + nn * 64 + m0 + 4);
        f32x4 b2 = ld4(mvb + nn * 64 + m0 + 8), b3 = ld4(mvb + nn * 64 + m0 + 12);
        f16x8 k0, k1, v0, v1;
#pragma unroll
        for (int i = 0; i < 4; ++i) {
            k0[i] = (_Float16)a0[i]; k0[i + 4] = (_Float16)a1[i];
            k1[i] = (_Float16)a2[i]; k1[i + 4] = (_Float16)a3[i];
            v0[i] = (_Float16)b0[i]; v0[i + 4] = (_Float16)b1[i];
            v1[i] = (_Float16)b2[i]; v1[i + 4] = (_Float16)b3[i];
        }
        *(f16x8*)&mks[nn][m0]     = k0;
        *(f16x8*)&mks[nn][m0 + 8] = k1;
        *(f16x8*)&mvs[nn][m0]     = v0;
        *(f16x8*)&mvs[nn][m0 + 8] = v1;
    }
    __syncthreads();
    const int w = t >> 6, l = t & 63, lr = l & 15, lk = l >> 4;
    f32x4 acc[4] = {};
#pragma unroll
    for (int kn = 0; kn < 2; ++kn) {
        f16x8 bfr = *(const f16x8*)&mks[16 * w + lr][kn * 32 + lk * 8];
#pragma unroll
        for (int di = 0; di < 4; ++di) {
            f16x8 afr = *(const f16x8*)&mvs[16 * di + lr][kn * 32 + lk * 8];
            acc[di] = __builtin_amdgcn_mfma_f32_16x16x32_f16(afr, bfr, acc[di], 0, 0, 0);
        }
    }
#pragma unroll
    for (int di = 0; di < 4; ++di)
#pragma unroll
        for (int r = 0; r < 4; ++r)
            Wb[h * 4096 + (16 * di + 4 * lk + r) * 64 + 16 * w + lr] = (_Float16)acc[di][r];
    {
        const int m = t & 63, n0 = (t >> 6) * 16;
        f16x8 x0, x1;
#pragma unroll
        for (int i = 0; i < 8; ++i) { x0[i] = mks[n0 + i][m]; x1[i] = mks[n0 + 8 + i][m]; }
        *(f16x8*)&mkTb[h * 4096 + m * 64 + n0]     = x0;
        *(f16x8*)&mkTb[h * 4096 + m * 64 + n0 + 8] = x1;
    }
}

// ---------------------------------------------------------------------------
// Mega kernel (R10 structure — wall-clock best — with CACHED q loads).
//  Blocks [0, nbR): reduction over key/value tiles (grid-stride, prefetched,
//  nt streaming loads).
//  Blocks [nbR, nbR+8192): fused path, BARRIER-FREE and LDS-FREE:
//    A-fragments loaded directly from q with REGULAR (cached) loads so q can
//    stay resident in L2/L3 across iterations (k/v stream nt, outputs stream
//    nt -> q is the tensor that should own the cache). The 4 waves read
//    identical fragments -> L1 serves repeats (issue cost ~1us, negligible).
//    B-operands (mkT, W) register-resident from the L2-hot prep buffers.
// ---------------------------------------------------------------------------
__global__ __launch_bounds__(256) void mega(
    const float* __restrict__ q,   const float* __restrict__ key,
    const float* __restrict__ val, const _Float16* __restrict__ mkTb,
    const float* __restrict__ mnorm, const _Float16* __restrict__ Wb,
    float* __restrict__ out_mo, float* __restrict__ out_sc,
    float* __restrict__ skp, float* __restrict__ svp, float* __restrict__ pbp,
    const int nbR)
{
    __shared__ struct { float ktile[64][68]; float red[256]; float ks[64]; } smr;

    const int t   = threadIdx.x;
    const int bid = blockIdx.x;

    if (bid < nbR) {
        // ================= reduction path =================
        const int r0 = t >> 4;
        const int c0 = (t & 15) << 2;
        f32x4 ska[4] = {}; f32x4 sva[4] = {};
        float pba[4] = {0.f, 0.f, 0.f, 0.f};
        f32x4 ka[4], va[4];
        int i = bid;
#pragma unroll
        for (int qq = 0; qq < 4; ++qq) {
            const int row = r0 + 16 * qq;
            ka[qq] = ntld4(key + (size_t)i * 4096 + row * 64 + c0);
            va[qq] = ntld4(val + (size_t)i * 4096 + row * 64 + c0);
        }
        while (true) {
            const int inx = i + nbR;
            const bool more = (inx < 8192);
            f32x4 kn4[4], vn4[4];
            if (more) {
#pragma unroll
                for (int qq = 0; qq < 4; ++qq) {
                    const int row = r0 + 16 * qq;
                    kn4[qq] = ntld4(key + (size_t)inx * 4096 + row * 64 + c0);
                    vn4[qq] = ntld4(val + (size_t)inx * 4096 + row * 64 + c0);
                }
            }
#pragma unroll
            for (int qq = 0; qq < 4; ++qq) {
                const int row = r0 + 16 * qq;
                ska[qq] += ka[qq];
                sva[qq] += va[qq];
                *(f32x4*)&smr.ktile[row][c0] = ka[qq];
            }
            __syncthreads();
            {   // ks[d] = sum_n ktile[n][d]
                const int d  = t & 63;
                const int rr = (t >> 6) * 16;
                float p = 0.f;
#pragma unroll
                for (int r = 0; r < 16; ++r) p += smr.ktile[rr + r][d];
                smr.red[t] = p;
            }
            __syncthreads();
            if (t < 64)
                smr.ks[t] = smr.red[t] + smr.red[t + 64] + smr.red[t + 128] + smr.red[t + 192];
            __syncthreads();
#pragma unroll
            for (int qq = 0; qq < 4; ++qq) {
                float pq = va[qq][0] * smr.ks[c0]     + va[qq][1] * smr.ks[c0 + 1]
                         + va[qq][2] * smr.ks[c0 + 2] + va[qq][3] * smr.ks[c0 + 3];
                pq += __shfl_xor(pq, 1);
                pq += __shfl_xor(pq, 2);
                pq += __shfl_xor(pq, 4);
                pq += __shfl_xor(pq, 8);
                pba[qq] += pq;
            }
            if (!more) break;
#pragma unroll
            for (int qq = 0; qq < 4; ++qq) { ka[qq] = kn4[qq]; va[qq] = vn4[qq]; }
            i = inx;
        }
        const size_t pb4 = (size_t)bid * 4096;
#pragma unroll
        for (int qq = 0; qq < 4; ++qq) {
            ntst4(skp + pb4 + 4 * t + 1024 * qq, ska[qq]);
            ntst4(svp + pb4 + 4 * t + 1024 * qq, sva[qq]);
        }
        if ((t & 15) == 0) {
#pragma unroll
            for (int qq = 0; qq < 4; ++qq)
                pbp[bid * 64 + r0 + 16 * qq] = pba[qq];
        }
        return;
    }

    // ================= fused path (barrier-free, LDS-free) =================
    const int fid = bid - nbR;
    const int h   = fid >> 7;          // h-major
    const int b   = fid & 127;
    const int bh  = b * 64 + h;
    const float* qb = q + (size_t)bh * 4096;

    const int w  = t >> 6;
    const int l  = t & 63;
    const int lr = l & 15;
    const int lk = l >> 4;

    // B-operand fragments from prep buffers (L2-hot, 16-B vector loads)
    f16x8 bfrK[2], bfrW[2];
    {
        const _Float16* mrow = mkTb + h * 4096 + (16 * w + lr) * 64 + lk * 8;
        const _Float16* wrow = Wb   + h * 4096 + (16 * w + lr) * 64 + lk * 8;
        bfrK[0] = *(const f16x8*)(mrow);
        bfrK[1] = *(const f16x8*)(mrow + 32);
        bfrW[0] = *(const f16x8*)(wrow);
        bfrW[1] = *(const f16x8*)(wrow + 32);
    }
    // per-thread output scale: scl[di][r] = 1/(mnorm[16di+4lk+r]+1e-6)
    f32x4 scl[4];
#pragma unroll
    for (int di = 0; di < 4; ++di) {
        f32x4 nv = ld4(mnorm + 16 * di + 4 * lk);
#pragma unroll
        for (int r = 0; r < 4; ++r) scl[di][r] = __builtin_amdgcn_rcpf(nv[r] + 1e-6f);
    }

    // A-fragments straight from global, CACHED loads (q owns the L2/L3):
    // afr[di][kn][e] = q[kn*32+lk*8+e][16di+lr]
    f16x8 afr[4][2];
#pragma unroll
    for (int di = 0; di < 4; ++di) {
        const float* qcol = qb + 16 * di + lr;
#pragma unroll
        for (int kn = 0; kn < 2; ++kn) {
            const float* p0 = qcol + (kn * 32 + lk * 8) * 64;
            f16x8 a;
#pragma unroll
            for (int e = 0; e < 8; ++e) a[e] = (_Float16)p0[e * 64];
            afr[di][kn] = a;
        }
    }

    f32x4 accS[4] = {}, accO[4] = {};
#pragma unroll
    for (int kn = 0; kn < 2; ++kn) {
#pragma unroll
        for (int di = 0; di < 4; ++di) {
            accS[di] = __builtin_amdgcn_mfma_f32_16x16x32_f16(afr[di][kn], bfrK[kn], accS[di], 0, 0, 0);
            accO[di] = __builtin_amdgcn_mfma_f32_16x16x32_f16(afr[di][kn], bfrW[kn], accO[di], 0, 0, 0);
        }
    }

    // D layout: row = d (16di+4lk+r), col = m (16w+lr) -> f32x4 nt stores
    const int m = 16 * w + lr;
    const size_t gbase = (size_t)bh * 4096;
#pragma unroll
    for (int di = 0; di < 4; ++di) {
        const int d0 = 16 * di + 4 * lk;
        f32x4 sv, ov;
#pragma unroll
        for (int r = 0; r < 4; ++r) {
            sv[r] = accS[di][r] * scl[di][r];
            ov[r] = accO[di][r] * scl[di][r];
        }
        ntst4(out_sc + gbase + (size_t)m * 64 + d0, sv);
        ntst4(out_mo + gbase + (size_t)m * 64 + d0, ov);
    }
}

// Stage 2: NC n-chunks x 33 strips -> p2[NC][8256]
#define NCHUNK 8
__global__ __launch_bounds__(256) void reduce2(
    const float* __restrict__ skp, const float* __restrict__ svp,
    const float* __restrict__ pbp, float* __restrict__ p2,
    const int nbR, const int clen)
{
    const int bi = blockIdx.x;
    const int c  = bi / 33;
    const int e  = (bi % 33) * 256 + threadIdx.x;
    if (e >= 8256) return;
    int n0 = c * clen;
    int n1 = n0 + clen; if (n1 > nbR) n1 = nbR;
    float s = 0.f;
    if (e < 4096) {
        for (int n = n0; n < n1; ++n) s += skp[(size_t)n * 4096 + e];
    } else if (e < 8192) {
        const int e2 = e - 4096;
        for (int n = n0; n < n1; ++n) s += svp[(size_t)n * 4096 + e2];
    } else {
        const int e2 = e - 8192;
        for (int n = n0; n < n1; ++n) s += pbp[n * 64 + e2];
    }
    p2[c * 8256 + e] = s;
}

// Stage 3: finalize — sum the NC chunks, norms, compression factor, outputs.
__global__ __launch_bounds__(256) void finalize(
    const float* __restrict__ p2, const float* __restrict__ mnorm,
    const float* __restrict__ crate,
    float* __restrict__ out_nmk, float* __restrict__ out_nmn)
{
    __shared__ float tot[8256];
    __shared__ float fac_s[64];
    const int t = threadIdx.x;
    for (int e = t; e < 8256; e += 256) {
        float s = 0.f;
#pragma unroll
        for (int c = 0; c < NCHUNK; ++c) s += p2[c * 8256 + e];
        tot[e] = s;
    }
    __syncthreads();
    const float* sk_tot = tot;
    const float* sv_tot = tot + 4096;
    const float* pb_tot = tot + 8192;
    if (t < 64) {
        float ss = 0.f;
#pragma unroll 8
        for (int dd = 0; dd < 64; ++dd) {
            float mkm = sk_tot[t * 64 + dd] * (1.0f / 8192.0f);
            ss += mkm * mkm;
        }
        const float nmn = mnorm[t] + sqrtf(ss);
        float v = nmn;
        for (int off = 32; off; off >>= 1) v += __shfl_xor(v, off);
        const float mean = v * (1.0f / 64.0f);
        const float f = (mean > 0.9f) ? crate[t] : 1.0f;
        fac_s[t] = f;
        out_nmn[t] = nmn * f;
    }
    __syncthreads();
    for (int e = t; e < 4096; e += 256) {
        const int jh = e >> 6;
        const float mb = pb_tot[jh] * (1.0f / 524288.0f);   // mean binding
        const float mvv = sv_tot[e] * (1.0f / 8192.0f);     // mean value
        out_nmk[e] = mb * mvv * fac_s[jh];
    }
}

extern "C" void kernel_launch(void* const* d_in, const int* in_sizes, int n_in,
                              void* d_out, int out_size, void* d_ws, size_t ws_size,
                              hipStream_t stream) {
    const float* q  = (const float*)d_in[0];
    const float* k  = (const float*)d_in[1];
    const float* v  = (const float*)d_in[2];
    const float* mk = (const float*)d_in[3];
    const float* mn = (const float*)d_in[4];
    const float* mv = (const float*)d_in[5];
    const float* cr = (const float*)d_in[6];

    float* out     = (float*)d_out;
    float* out_mo  = out;                    // [128,64,64,64]
    float* out_sc  = out + 33554432;         // [128,64,64,64]
    float* out_nmk = out + 67108864;         // [64,64]
    float* out_nmn = out + 67112960;         // [64]

    float* ws   = (float*)d_ws;
    float* p2   = ws;                        // NCHUNK*8256 floats
    _Float16* mkTb = (_Float16*)(ws + NCHUNK * 8256);   // 262144 halves
    _Float16* Wb   = mkTb + 64 * 4096;                  // 262144 halves
    float* part = ws + NCHUNK * 8256 + 262144;
    const size_t wsf = ws_size / 4;
    const size_t used = NCHUNK * 8256 + 262144;
    const size_t avail = (wsf > used) ? (wsf - used) : 0;
    int nb = (int)(avail / 8256);
    if (nb > 256) nb = 256;
    if (nb < 1)   nb = 1;
    float* skp = part;
    float* svp = part + (size_t)nb * 4096;
    float* pbp = svp  + (size_t)nb * 4096;
    const int clen = (nb + NCHUNK - 1) / NCHUNK;

    hipLaunchKernelGGL(prep, dim3(64), dim3(256), 0, stream,
                       mk, mv, mkTb, Wb);
    hipLaunchKernelGGL(mega, dim3(nb + 8192), dim3(256), 0, stream,
                       q, k, v, mkTb, mn, Wb, out_mo, out_sc, skp, svp, pbp, nb);
    hipLaunchKernelGGL(reduce2, dim3(33 * NCHUNK), dim3(256), 0, stream,
                       skp, svp, pbp, p2, nb, clen);
    hipLaunchKernelGGL(finalize, dim3(1), dim3(256), 0, stream,
                       p2, mn, cr, out_nmk, out_nmn);
}

// Round 14
// 141.374 us; speedup vs baseline: 1.3860x; 1.1123x over previous
//
#include <hip/hip_runtime.h>
#include <hip/hip_fp16.h>

typedef _Float16 f16x8 __attribute__((ext_vector_type(8)));
typedef float f32x4 __attribute__((ext_vector_type(4)));

__device__ __forceinline__ f32x4 ntld4(const float* p) {
    return __builtin_nontemporal_load((const f32x4*)p);
}
__device__ __forceinline__ f32x4 ld4(const float* p) {
    return *(const f32x4*)p;
}
__device__ __forceinline__ void ntst4(float* p, f32x4 v) {
    __builtin_nontemporal_store(v, (f32x4*)p);
}

// ---------------------------------------------------------------------------
// prep: per head h, W[h] = mv[h] @ mk[h]^T (f16 [n][n']) and mkT[h] (f16
// [m][n]) into workspace. norm-divide commutes (depends only on d), so both
// outputs become GEMMs against q with contraction over n.
// ---------------------------------------------------------------------------
__global__ __launch_bounds__(256) void prep(
    const float* __restrict__ mk, const float* __restrict__ mv,
    _Float16* __restrict__ mkTb, _Float16* __restrict__ Wb)
{
    __shared__ _Float16 mks[64][72];
    __shared__ _Float16 mvs[64][72];
    const int t = threadIdx.x;
    const int h = blockIdx.x;
    const float* mkb = mk + h * 4096;
    const float* mvb = mv + h * 4096;
    {
        const int nn = t >> 2, m0 = (t & 3) * 16;
        f32x4 a0 = ld4(mkb + nn * 64 + m0),     a1 = ld4(mkb + nn * 64 + m0 + 4);
        f32x4 a2 = ld4(mkb + nn * 64 + m0 + 8), a3 = ld4(mkb + nn * 64 + m0 + 12);
        f32x4 b0 = ld4(mvb + nn * 64 + m0),     b1 = ld4(mvb + nn * 64 + m0 + 4);
        f32x4 b2 = ld4(mvb + nn * 64 + m0 + 8), b3 = ld4(mvb + nn * 64 + m0 + 12);
        f16x8 k0, k1, v0, v1;
#pragma unroll
        for (int i = 0; i < 4; ++i) {
            k0[i] = (_Float16)a0[i]; k0[i + 4] = (_Float16)a1[i];
            k1[i] = (_Float16)a2[i]; k1[i + 4] = (_Float16)a3[i];
            v0[i] = (_Float16)b0[i]; v0[i + 4] = (_Float16)b1[i];
            v1[i] = (_Float16)b2[i]; v1[i + 4] = (_Float16)b3[i];
        }
        *(f16x8*)&mks[nn][m0]     = k0;
        *(f16x8*)&mks[nn][m0 + 8] = k1;
        *(f16x8*)&mvs[nn][m0]     = v0;
        *(f16x8*)&mvs[nn][m0 + 8] = v1;
    }
    __syncthreads();
    const int w = t >> 6, l = t & 63, lr = l & 15, lk = l >> 4;
    f32x4 acc[4] = {};
#pragma unroll
    for (int kn = 0; kn < 2; ++kn) {
        f16x8 bfr = *(const f16x8*)&mks[16 * w + lr][kn * 32 + lk * 8];
#pragma unroll
        for (int di = 0; di < 4; ++di) {
            f16x8 afr = *(const f16x8*)&mvs[16 * di + lr][kn * 32 + lk * 8];
            acc[di] = __builtin_amdgcn_mfma_f32_16x16x32_f16(afr, bfr, acc[di], 0, 0, 0);
        }
    }
#pragma unroll
    for (int di = 0; di < 4; ++di)
#pragma unroll
        for (int r = 0; r < 4; ++r)
            Wb[h * 4096 + (16 * di + 4 * lk + r) * 64 + 16 * w + lr] = (_Float16)acc[di][r];
    {
        const int m = t & 63, n0 = (t >> 6) * 16;
        f16x8 x0, x1;
#pragma unroll
        for (int i = 0; i < 8; ++i) { x0[i] = mks[n0 + i][m]; x1[i] = mks[n0 + 8 + i][m]; }
        *(f16x8*)&mkTb[h * 4096 + m * 64 + n0]     = x0;
        *(f16x8*)&mkTb[h * 4096 + m * 64 + n0 + 8] = x1;
    }
}

// ---------------------------------------------------------------------------
// Mega kernel (R13 + wave-private LDS store-coalescing).
//  Blocks [0, nbR): reduction over key/value tiles (grid-stride, prefetched).
//  Blocks [nbR, nbR+8192): fused path, barrier-free:
//    A-fragments from q (cached loads), B-operands (mkT, W) in registers.
//    NEW: outputs are staged through a wave-private 4 KB LDS slab so every
//    global store instruction writes 1 KB FULLY CONTIGUOUS (full lines, no
//    partial-sector nt streams). Wave-internal lgkmcnt ordering only — no
//    __syncthreads in the fused path.
//    LDS write: lane l, frag di -> slot di*64+l          (64 distinct slots)
//    LDS read:  lane l, inst i -> slot (u>>2)*64+(u&3)*16+i*4+hi, u=l&15
//    store:     lane l, inst i -> subtile + i*1024B + l*16B (contiguous)
// ---------------------------------------------------------------------------
__global__ __launch_bounds__(256) void mega(
    const float* __restrict__ q,   const float* __restrict__ key,
    const float* __restrict__ val, const _Float16* __restrict__ mkTb,
    const float* __restrict__ mnorm, const _Float16* __restrict__ Wb,
    float* __restrict__ out_mo, float* __restrict__ out_sc,
    float* __restrict__ skp, float* __restrict__ svp, float* __restrict__ pbp,
    const int nbR)
{
    __shared__ union SM {
        struct { float stg[4][1024]; } f;                                  // 16 KB
        struct { float ktile[64][68]; float red[256]; float ks[64]; } r;   // 18.7 KB
    } sm;

    const int t   = threadIdx.x;
    const int bid = blockIdx.x;

    if (bid < nbR) {
        // ================= reduction path =================
        const int r0 = t >> 4;
        const int c0 = (t & 15) << 2;
        f32x4 ska[4] = {}; f32x4 sva[4] = {};
        float pba[4] = {0.f, 0.f, 0.f, 0.f};
        f32x4 ka[4], va[4];
        int i = bid;
#pragma unroll
        for (int qq = 0; qq < 4; ++qq) {
            const int row = r0 + 16 * qq;
            ka[qq] = ntld4(key + (size_t)i * 4096 + row * 64 + c0);
            va[qq] = ntld4(val + (size_t)i * 4096 + row * 64 + c0);
        }
        while (true) {
            const int inx = i + nbR;
            const bool more = (inx < 8192);
            f32x4 kn4[4], vn4[4];
            if (more) {
#pragma unroll
                for (int qq = 0; qq < 4; ++qq) {
                    const int row = r0 + 16 * qq;
                    kn4[qq] = ntld4(key + (size_t)inx * 4096 + row * 64 + c0);
                    vn4[qq] = ntld4(val + (size_t)inx * 4096 + row * 64 + c0);
                }
            }
#pragma unroll
            for (int qq = 0; qq < 4; ++qq) {
                const int row = r0 + 16 * qq;
                ska[qq] += ka[qq];
                sva[qq] += va[qq];
                *(f32x4*)&sm.r.ktile[row][c0] = ka[qq];
            }
            __syncthreads();
            {   // ks[d] = sum_n ktile[n][d]
                const int d  = t & 63;
                const int rr = (t >> 6) * 16;
                float p = 0.f;
#pragma unroll
                for (int r = 0; r < 16; ++r) p += sm.r.ktile[rr + r][d];
                sm.r.red[t] = p;
            }
            __syncthreads();
            if (t < 64)
                sm.r.ks[t] = sm.r.red[t] + sm.r.red[t + 64] + sm.r.red[t + 128] + sm.r.red[t + 192];
            __syncthreads();
#pragma unroll
            for (int qq = 0; qq < 4; ++qq) {
                float pq = va[qq][0] * sm.r.ks[c0]     + va[qq][1] * sm.r.ks[c0 + 1]
                         + va[qq][2] * sm.r.ks[c0 + 2] + va[qq][3] * sm.r.ks[c0 + 3];
                pq += __shfl_xor(pq, 1);
                pq += __shfl_xor(pq, 2);
                pq += __shfl_xor(pq, 4);
                pq += __shfl_xor(pq, 8);
                pba[qq] += pq;
            }
            if (!more) break;
#pragma unroll
            for (int qq = 0; qq < 4; ++qq) { ka[qq] = kn4[qq]; va[qq] = vn4[qq]; }
            i = inx;
        }
        const size_t pb4 = (size_t)bid * 4096;
#pragma unroll
        for (int qq = 0; qq < 4; ++qq) {
            ntst4(skp + pb4 + 4 * t + 1024 * qq, ska[qq]);
            ntst4(svp + pb4 + 4 * t + 1024 * qq, sva[qq]);
        }
        if ((t & 15) == 0) {
#pragma unroll
            for (int qq = 0; qq < 4; ++qq)
                pbp[bid * 64 + r0 + 16 * qq] = pba[qq];
        }
        return;
    }

    // ================= fused path (barrier-free) =================
    const int fid = bid - nbR;
    const int h   = fid >> 7;          // h-major
    const int b   = fid & 127;
    const int bh  = b * 64 + h;
    const float* qb = q + (size_t)bh * 4096;

    const int w  = t >> 6;
    const int l  = t & 63;
    const int lr = l & 15;
    const int lk = l >> 4;
    const int u  = l & 15;
    const int hi = l >> 4;

    // B-operand fragments from prep buffers (L2-hot, 16-B vector loads)
    f16x8 bfrK[2], bfrW[2];
    {
        const _Float16* mrow = mkTb + h * 4096 + (16 * w + lr) * 64 + lk * 8;
        const _Float16* wrow = Wb   + h * 4096 + (16 * w + lr) * 64 + lk * 8;
        bfrK[0] = *(const f16x8*)(mrow);
        bfrK[1] = *(const f16x8*)(mrow + 32);
        bfrW[0] = *(const f16x8*)(wrow);
        bfrW[1] = *(const f16x8*)(wrow + 32);
    }
    // per-thread output scale: scl[di][r] = 1/(mnorm[16di+4lk+r]+1e-6)
    f32x4 scl[4];
#pragma unroll
    for (int di = 0; di < 4; ++di) {
        f32x4 nv = ld4(mnorm + 16 * di + 4 * lk);
#pragma unroll
        for (int r = 0; r < 4; ++r) scl[di][r] = __builtin_amdgcn_rcpf(nv[r] + 1e-6f);
    }

    // A-fragments straight from global: afr[di][kn][e] = q[kn*32+lk*8+e][16di+lr]
    f16x8 afr[4][2];
#pragma unroll
    for (int di = 0; di < 4; ++di) {
        const float* qcol = qb + 16 * di + lr;
#pragma unroll
        for (int kn = 0; kn < 2; ++kn) {
            const float* p0 = qcol + (kn * 32 + lk * 8) * 64;
            f16x8 a;
#pragma unroll
            for (int e = 0; e < 8; ++e) a[e] = (_Float16)p0[e * 64];
            afr[di][kn] = a;
        }
    }

    f32x4 accS[4] = {}, accO[4] = {};
#pragma unroll
    for (int kn = 0; kn < 2; ++kn) {
#pragma unroll
        for (int di = 0; di < 4; ++di) {
            accS[di] = __builtin_amdgcn_mfma_f32_16x16x32_f16(afr[di][kn], bfrK[kn], accS[di], 0, 0, 0);
            accO[di] = __builtin_amdgcn_mfma_f32_16x16x32_f16(afr[di][kn], bfrW[kn], accO[di], 0, 0, 0);
        }
    }

    const size_t gsub_sc = (size_t)bh * 4096 + 16 * w * 64;   // wave's subtile base
    const size_t gsub_mo = gsub_sc;
    float* stg = sm.f.stg[w];
    const int rd_off = ((u >> 2) * 256) + ((u & 3) * 16 + hi) * 4;   // + i*16 floats... (i*4)*4

    // ---- output 1: scores -> LDS slab -> contiguous nt stores ----
#pragma unroll
    for (int di = 0; di < 4; ++di) {
        f32x4 sv;
#pragma unroll
        for (int r = 0; r < 4; ++r) sv[r] = accS[di][r] * scl[di][r];
        *(f32x4*)&stg[di * 256 + l * 4] = sv;
    }
#pragma unroll
    for (int i = 0; i < 4; ++i) {
        f32x4 pv = *(const f32x4*)&stg[rd_off + i * 16];
        ntst4(out_sc + gsub_sc + i * 256 + l * 4, pv);
    }

    // ---- output 2: out_mo (reuse slab; wave-serial, lgkmcnt-ordered) ----
#pragma unroll
    for (int di = 0; di < 4; ++di) {
        f32x4 ov;
#pragma unroll
        for (int r = 0; r < 4; ++r) ov[r] = accO[di][r] * scl[di][r];
        *(f32x4*)&stg[di * 256 + l * 4] = ov;
    }
#pragma unroll
    for (int i = 0; i < 4; ++i) {
        f32x4 pv = *(const f32x4*)&stg[rd_off + i * 16];
        ntst4(out_mo + gsub_mo + i * 256 + l * 4, pv);
    }
}

// Stage 2: NC n-chunks x 33 strips -> p2[NC][8256]
#define NCHUNK 8
__global__ __launch_bounds__(256) void reduce2(
    const float* __restrict__ skp, const float* __restrict__ svp,
    const float* __restrict__ pbp, float* __restrict__ p2,
    const int nbR, const int clen)
{
    const int bi = blockIdx.x;
    const int c  = bi / 33;
    const int e  = (bi % 33) * 256 + threadIdx.x;
    if (e >= 8256) return;
    int n0 = c * clen;
    int n1 = n0 + clen; if (n1 > nbR) n1 = nbR;
    float s = 0.f;
    if (e < 4096) {
        for (int n = n0; n < n1; ++n) s += skp[(size_t)n * 4096 + e];
    } else if (e < 8192) {
        const int e2 = e - 4096;
        for (int n = n0; n < n1; ++n) s += svp[(size_t)n * 4096 + e2];
    } else {
        const int e2 = e - 8192;
        for (int n = n0; n < n1; ++n) s += pbp[n * 64 + e2];
    }
    p2[c * 8256 + e] = s;
}

// Stage 3: finalize — sum the NC chunks, norms, compression factor, outputs.
__global__ __launch_bounds__(256) void finalize(
    const float* __restrict__ p2, const float* __restrict__ mnorm,
    const float* __restrict__ crate,
    float* __restrict__ out_nmk, float* __restrict__ out_nmn)
{
    __shared__ float tot[8256];
    __shared__ float fac_s[64];
    const int t = threadIdx.x;
    for (int e = t; e < 8256; e += 256) {
        float s = 0.f;
#pragma unroll
        for (int c = 0; c < NCHUNK; ++c) s += p2[c * 8256 + e];
        tot[e] = s;
    }
    __syncthreads();
    const float* sk_tot = tot;
    const float* sv_tot = tot + 4096;
    const float* pb_tot = tot + 8192;
    if (t < 64) {
        float ss = 0.f;
#pragma unroll 8
        for (int dd = 0; dd < 64; ++dd) {
            float mkm = sk_tot[t * 64 + dd] * (1.0f / 8192.0f);
            ss += mkm * mkm;
        }
        const float nmn = mnorm[t] + sqrtf(ss);
        float v = nmn;
        for (int off = 32; off; off >>= 1) v += __shfl_xor(v, off);
        const float mean = v * (1.0f / 64.0f);
        const float f = (mean > 0.9f) ? crate[t] : 1.0f;
        fac_s[t] = f;
        out_nmn[t] = nmn * f;
    }
    __syncthreads();
    for (int e = t; e < 4096; e += 256) {
        const int jh = e >> 6;
        const float mb = pb_tot[jh] * (1.0f / 524288.0f);   // mean binding
        const float mvv = sv_tot[e] * (1.0f / 8192.0f);     // mean value
        out_nmk[e] = mb * mvv * fac_s[jh];
    }
}

extern "C" void kernel_launch(void* const* d_in, const int* in_sizes, int n_in,
                              void* d_out, int out_size, void* d_ws, size_t ws_size,
                              hipStream_t stream) {
    const float* q  = (const float*)d_in[0];
    const float* k  = (const float*)d_in[1];
    const float* v  = (const float*)d_in[2];
    const float* mk = (const float*)d_in[3];
    const float* mn = (const float*)d_in[4];
    const float* mv = (const float*)d_in[5];
    const float* cr = (const float*)d_in[6];

    float* out     = (float*)d_out;
    float* out_mo  = out;                    // [128,64,64,64]
    float* out_sc  = out + 33554432;         // [128,64,64,64]
    float* out_nmk = out + 67108864;         // [64,64]
    float* out_nmn = out + 67112960;         // [64]

    float* ws   = (float*)d_ws;
    float* p2   = ws;                        // NCHUNK*8256 floats
    _Float16* mkTb = (_Float16*)(ws + NCHUNK * 8256);   // 262144 halves
    _Float16* Wb   = mkTb + 64 * 4096;                  // 262144 halves
    float* part = ws + NCHUNK * 8256 + 262144;
    const size_t wsf = ws_size / 4;
    const size_t used = NCHUNK * 8256 + 262144;
    const size_t avail = (wsf > used) ? (wsf - used) : 0;
    int nb = (int)(avail / 8256);
    if (nb > 256) nb = 256;
    if (nb < 1)   nb = 1;
    float* skp = part;
    float* svp = part + (size_t)nb * 4096;
    float* pbp = svp  + (size_t)nb * 4096;
    const int clen = (nb + NCHUNK - 1) / NCHUNK;

    hipLaunchKernelGGL(prep, dim3(64), dim3(256), 0, stream,
                       mk, mv, mkTb, Wb);
    hipLaunchKernelGGL(mega, dim3(nb + 8192), dim3(256), 0, stream,
                       q, k, v, mkTb, mn, Wb, out_mo, out_sc, skp, svp, pbp, nb);
    hipLaunchKernelGGL(reduce2, dim3(33 * NCHUNK), dim3(256), 0, stream,
                       skp, svp, pbp, p2, nb, clen);
    hipLaunchKernelGGL(finalize, dim3(1), dim3(256), 0, stream,
                       p2, mn, cr, out_nmk, out_nmn);
}